// Round 1
// baseline (3021.128 us; speedup 1.0000x reference)
//
#include <hip/hip_runtime.h>
#include <math.h>

#define NN 50000
#define HH 256
#define FIN 128
#define CC 112
#define LL 8
#define EE 800000
#define EPSB 1e-5f

// ---------------- CSR build ----------------
__global__ void k_count(const int* __restrict__ col, int* __restrict__ cnt, int E) {
    int e = blockIdx.x * blockDim.x + threadIdx.x;
    if (e < E) atomicAdd(&cnt[col[e]], 1);
}

// single-block exclusive scan over n counts -> rp[0..n]
__global__ void k_exscan(const int* __restrict__ cnt, int* __restrict__ rp, int n) {
    __shared__ int sm[256];
    int tid = threadIdx.x;
    int chunk = (n + 255) >> 8;
    int b = tid * chunk;
    int e = b + chunk; if (e > n) e = n; if (b > n) b = n;
    int s = 0;
    for (int i = b; i < e; ++i) s += cnt[i];
    sm[tid] = s;
    __syncthreads();
    if (tid == 0) {
        int run = 0;
        for (int i = 0; i < 256; ++i) { int v = sm[i]; sm[i] = run; run += v; }
    }
    __syncthreads();
    int off = sm[tid];
    for (int i = b; i < e; ++i) { rp[i] = off; off += cnt[i]; }
    if (tid == 255) rp[n] = off;
}

__global__ void k_fill(const int* __restrict__ row, const int* __restrict__ col,
                       const int* __restrict__ rp, int* __restrict__ cur,
                       int* __restrict__ src, int E) {
    int e = blockIdx.x * blockDim.x + threadIdx.x;
    if (e >= E) return;
    int c = col[e];
    int pos = rp[c] + atomicAdd(&cur[c], 1);
    src[pos] = row[e];
}

__global__ void k_dinv(const int* __restrict__ rp, float* __restrict__ dinv, int n) {
    int v = blockIdx.x * blockDim.x + threadIdx.x;
    if (v < n) dinv[v] = rsqrtf((float)(rp[v + 1] - rp[v] + 1));  // +1 self-loop
}

// ---------------- fp32 tiled GEMM: C[M,Nc] = A[M,K] @ B[K,Nc] + bias ----------------
#define BM 128
#define BN 128
#define BK 16

__global__ __launch_bounds__(256) void k_gemm(const float* __restrict__ A,
                                              const float* __restrict__ B,
                                              const float* __restrict__ bias,
                                              float* __restrict__ C,
                                              int M, int Nc, int K) {
    __shared__ float As[BK][BM + 4];
    __shared__ float Bs[BK][BN + 4];
    const int m0 = blockIdx.x * BM;
    const int n0 = blockIdx.y * BN;
    const int tid = threadIdx.x;
    const int tx = tid & 15;
    const int ty = tid >> 4;
    float acc[8][8];
#pragma unroll
    for (int i = 0; i < 8; ++i)
#pragma unroll
        for (int j = 0; j < 8; ++j) acc[i][j] = 0.f;

    for (int k0 = 0; k0 < K; k0 += BK) {
        // A tile 128x16, transposed into As[k][m]
#pragma unroll
        for (int l = 0; l < 2; ++l) {
            int idx = tid + l * 256;
            int r = idx >> 2, c4 = (idx & 3) << 2;
            int gm = m0 + r;
            float4 v = make_float4(0.f, 0.f, 0.f, 0.f);
            if (gm < M) v = *(const float4*)(A + (size_t)gm * K + k0 + c4);
            As[c4 + 0][r] = v.x; As[c4 + 1][r] = v.y;
            As[c4 + 2][r] = v.z; As[c4 + 3][r] = v.w;
        }
        // B tile 16x128
#pragma unroll
        for (int l = 0; l < 2; ++l) {
            int idx = tid + l * 256;
            int r = idx >> 5, c4 = (idx & 31) << 2;
            int gn = n0 + c4;
            float4 v = make_float4(0.f, 0.f, 0.f, 0.f);
            if (gn < Nc) v = *(const float4*)(B + (size_t)(k0 + r) * Nc + gn);
            *(float4*)&Bs[r][c4] = v;
        }
        __syncthreads();
#pragma unroll
        for (int k = 0; k < BK; ++k) {
            float a[8], b[8];
            *(float4*)&a[0] = *(const float4*)&As[k][ty * 8];
            *(float4*)&a[4] = *(const float4*)&As[k][ty * 8 + 4];
            *(float4*)&b[0] = *(const float4*)&Bs[k][tx * 8];
            *(float4*)&b[4] = *(const float4*)&Bs[k][tx * 8 + 4];
#pragma unroll
            for (int i = 0; i < 8; ++i)
#pragma unroll
                for (int j = 0; j < 8; ++j)
                    acc[i][j] = fmaf(a[i], b[j], acc[i][j]);
        }
        __syncthreads();
    }
#pragma unroll
    for (int i = 0; i < 8; ++i) {
        int gm = m0 + ty * 8 + i;
        if (gm >= M) continue;
#pragma unroll
        for (int j = 0; j < 8; j += 4) {
            int gn = n0 + tx * 8 + j;
            if (gn < Nc) {  // Nc multiple of 4, float4 never straddles
                float4 v;
                v.x = acc[i][j + 0] + bias[gn + 0];
                v.y = acc[i][j + 1] + bias[gn + 1];
                v.z = acc[i][j + 2] + bias[gn + 2];
                v.w = acc[i][j + 3] + bias[gn + 3];
                *(float4*)(C + (size_t)gm * Nc + gn) = v;
            }
        }
    }
}

// ---------------- gather SpMM: h[v] = dinv[v]^2*t[v] + sum_e dinv[src]*dinv[v]*t[src] ----------------
__global__ __launch_bounds__(256) void k_spmm(const float* __restrict__ t,
                                              const int* __restrict__ rp,
                                              const int* __restrict__ src,
                                              const float* __restrict__ dinv,
                                              float* __restrict__ h) {
    int gt = blockIdx.x * blockDim.x + threadIdx.x;
    int v = gt >> 6;            // one wave (64 lanes) per node
    int lane = threadIdx.x & 63;
    if (v >= NN) return;
    int c = lane << 2;          // 4 cols per lane, 64*4 = 256 = H
    float dv = dinv[v];
    float4 a = *(const float4*)(t + (size_t)v * HH + c);
    float w0 = dv * dv;
    float4 accv;
    accv.x = a.x * w0; accv.y = a.y * w0; accv.z = a.z * w0; accv.w = a.w * w0;
    int beg = rp[v], end = rp[v + 1];
    for (int j = beg; j < end; ++j) {
        int s = src[j];                       // wave-uniform
        float w = dinv[s] * dv;
        float4 b = *(const float4*)(t + (size_t)s * HH + c);
        accv.x = fmaf(b.x, w, accv.x);
        accv.y = fmaf(b.y, w, accv.y);
        accv.z = fmaf(b.z, w, accv.z);
        accv.w = fmaf(b.w, w, accv.w);
    }
    *(float4*)(h + (size_t)v * HH + c) = accv;
}

// ---------------- BatchNorm stats: per-column sum / sumsq ----------------
#define RPB 128
__global__ void k_bnstats(const float* __restrict__ h, float* __restrict__ s,
                          float* __restrict__ q) {
    int col = threadIdx.x;       // 256 threads == H columns
    int r0 = blockIdx.x * RPB;
    int r1 = r0 + RPB; if (r1 > NN) r1 = NN;
    float sum = 0.f, sq = 0.f;
    for (int r = r0; r < r1; ++r) {
        float v = h[(size_t)r * HH + col];
        sum += v;
        sq = fmaf(v, v, sq);
    }
    atomicAdd(&s[col], sum);
    atomicAdd(&q[col], sq);
}

// ---------------- normalize + ReLU + weighted residual ----------------
__global__ void k_bnnorm(float* __restrict__ h, float* __restrict__ acc,
                         const float* __restrict__ s, const float* __restrict__ q,
                         const float* __restrict__ gamma, const float* __restrict__ beta,
                         const float* __restrict__ wArr, int layer) {
    int idx = blockIdx.x * blockDim.x + threadIdx.x;
    if (idx >= NN * (HH / 4)) return;
    int c = (idx & 63) << 2;
    const float invN = 1.0f / (float)NN;
    float w = wArr[layer];
    float4 hv = ((const float4*)h)[idx];
    float4 av = ((const float4*)acc)[idx];
    float* hp = &hv.x;
    float* ap = &av.x;
#pragma unroll
    for (int k = 0; k < 4; ++k) {
        float mu = s[c + k] * invN;
        float var = q[c + k] * invN - mu * mu;
        float g = gamma[layer * HH + c + k];
        float b = beta[layer * HH + c + k];
        float v = (hp[k] - mu) * rsqrtf(var + EPSB) * g + b;
        v = fmaxf(v, 0.f);
        ap[k] = fmaf(w, v, ap[k]);
        hp[k] = v;
    }
    ((float4*)h)[idx] = hv;
    ((float4*)acc)[idx] = av;
}

// ---------------- softmax of the 8 layer weights ----------------
__global__ void k_softmaxw(const float* __restrict__ lw, float* __restrict__ wArr) {
    if (threadIdx.x == 0 && blockIdx.x == 0) {
        float m = -3.0e38f;
        for (int i = 0; i < LL; ++i) m = fmaxf(m, lw[i]);
        float e[LL]; float sum = 0.f;
        for (int i = 0; i < LL; ++i) { e[i] = expf(lw[i] - m); sum += e[i]; }
        for (int i = 0; i < LL; ++i) wArr[i] = e[i] / sum;
    }
}

// ---------------- log_softmax rows (one wave per row, C=112) ----------------
__global__ __launch_bounds__(256) void k_logsoftmax(const float* __restrict__ z,
                                                    float* __restrict__ out) {
    int gt = blockIdx.x * blockDim.x + threadIdx.x;
    int v = gt >> 6;
    int lane = threadIdx.x & 63;
    if (v >= NN) return;
    const float* row = z + (size_t)v * CC;
    float v0 = row[lane];                                  // lane < 64 < 112
    float v1 = (lane + 64 < CC) ? row[lane + 64] : -3.0e38f;
    float m = fmaxf(v0, v1);
#pragma unroll
    for (int d = 1; d < 64; d <<= 1) m = fmaxf(m, __shfl_xor(m, d, 64));
    float e = expf(v0 - m) + ((lane + 64 < CC) ? expf(v1 - m) : 0.f);
#pragma unroll
    for (int d = 1; d < 64; d <<= 1) e += __shfl_xor(e, d, 64);
    float lse = m + logf(e);
    out[(size_t)v * CC + lane] = v0 - lse;
    if (lane + 64 < CC) out[(size_t)v * CC + lane + 64] = v1 - lse;
}

extern "C" void kernel_launch(void* const* d_in, const int* in_sizes, int n_in,
                              void* d_out, int out_size, void* d_ws, size_t ws_size,
                              hipStream_t stream) {
    const float* x     = (const float*)d_in[0];
    const int*   e1    = (const int*)d_in[1];
    const int*   e2    = (const int*)d_in[2];
    const float* inW   = (const float*)d_in[3];
    const float* inb   = (const float*)d_in[4];
    const float* convW = (const float*)d_in[5];
    const float* convB = (const float*)d_in[6];
    const float* gamma = (const float*)d_in[7];
    const float* beta  = (const float*)d_in[8];
    const float* outW  = (const float*)d_in[9];
    const float* outb  = (const float*)d_in[10];
    const float* lw    = (const float*)d_in[11];

    char* ws = (char*)d_ws;
    size_t off = 0;
    auto alloc = [&](size_t bytes) -> void* {
        void* p = ws + off;
        off = (off + bytes + 255) & ~(size_t)255;
        return p;
    };
    float* h     = (float*)alloc((size_t)NN * HH * 4);
    float* t     = (float*)alloc((size_t)NN * HH * 4);
    float* acc   = (float*)alloc((size_t)NN * HH * 4);
    float* dinv1 = (float*)alloc((size_t)NN * 4);
    float* dinv2 = (float*)alloc((size_t)NN * 4);
    int*   rp1   = (int*)alloc((size_t)(NN + 1) * 4);
    int*   rp2   = (int*)alloc((size_t)(NN + 1) * 4);
    int*   src1  = (int*)alloc((size_t)EE * 4);
    int*   src2  = (int*)alloc((size_t)EE * 4);
    int*   cnt   = (int*)alloc((size_t)NN * 4);
    float* bns   = (float*)alloc(HH * 4);
    float* bnq   = (float*)alloc(HH * 4);
    float* wArr  = (float*)alloc(64);

    const int EB = (EE + 255) / 256;
    const int NB = (NN + 255) / 256;

    // CSR for adjacency 1 (col = destination = e1[E..2E))
    hipMemsetAsync(cnt, 0, (size_t)NN * 4, stream);
    k_count<<<EB, 256, 0, stream>>>(e1 + EE, cnt, EE);
    k_exscan<<<1, 256, 0, stream>>>(cnt, rp1, NN);
    hipMemsetAsync(cnt, 0, (size_t)NN * 4, stream);
    k_fill<<<EB, 256, 0, stream>>>(e1, e1 + EE, rp1, cnt, src1, EE);
    k_dinv<<<NB, 256, 0, stream>>>(rp1, dinv1, NN);

    // CSR for adjacency 2
    hipMemsetAsync(cnt, 0, (size_t)NN * 4, stream);
    k_count<<<EB, 256, 0, stream>>>(e2 + EE, cnt, EE);
    k_exscan<<<1, 256, 0, stream>>>(cnt, rp2, NN);
    hipMemsetAsync(cnt, 0, (size_t)NN * 4, stream);
    k_fill<<<EB, 256, 0, stream>>>(e2, e2 + EE, rp2, cnt, src2, EE);
    k_dinv<<<NB, 256, 0, stream>>>(rp2, dinv2, NN);

    k_softmaxw<<<1, 64, 0, stream>>>(lw, wArr);

    const int MT = (NN + BM - 1) / BM;  // 391
    // input FC: h = x @ inW + inb
    dim3 gin(MT, HH / BN);
    k_gemm<<<gin, 256, 0, stream>>>(x, inW, inb, h, NN, HH, FIN);

    hipMemsetAsync(acc, 0, (size_t)NN * HH * 4, stream);

    const int SPB = (NN * 64 + 255) / 256;
    const int ELB = (NN * (HH / 4) + 255) / 256;
    for (int i = 0; i < LL; ++i) {
        dim3 gc(MT, HH / BN);
        k_gemm<<<gc, 256, 0, stream>>>(h, convW + (size_t)i * HH * HH, convB + (size_t)i * HH,
                                       t, NN, HH, HH);
        const int* rp = (i < LL / 2) ? rp1 : rp2;
        const int* sr = (i < LL / 2) ? src1 : src2;
        const float* dv = (i < LL / 2) ? dinv1 : dinv2;
        k_spmm<<<SPB, 256, 0, stream>>>(t, rp, sr, dv, h);
        hipMemsetAsync(bns, 0, HH * 4, stream);
        hipMemsetAsync(bnq, 0, HH * 4, stream);
        k_bnstats<<<(NN + RPB - 1) / RPB, 256, 0, stream>>>(h, bns, bnq);
        k_bnnorm<<<ELB, 256, 0, stream>>>(h, acc, bns, bnq, gamma, beta, wArr, i);
    }

    // out FC: logits(t) = acc @ outW + outb   [N, 112]
    dim3 gout(MT, 1);
    k_gemm<<<gout, 256, 0, stream>>>(acc, outW, outb, t, NN, CC, HH);
    k_logsoftmax<<<SPB, 256, 0, stream>>>(t, (float*)d_out);
}

// Round 2
// 2335.835 us; speedup vs baseline: 1.2934x; 1.2934x over previous
//
#include <hip/hip_runtime.h>
#include <math.h>

#define NN 50000
#define HH 256
#define FIN 128
#define CC 112
#define LL 8
#define EE 800000
#define EPSB 1e-5f

typedef unsigned short u16;
typedef unsigned int u32;
typedef __attribute__((ext_vector_type(8))) short bf16x8;
typedef __attribute__((ext_vector_type(4))) float f32x4;

__device__ __forceinline__ u16 f2bf(float f) {
    u32 u = __float_as_uint(f);
    u32 r = (u + 0x7FFFu + ((u >> 16) & 1u)) >> 16;   // RNE
    return (u16)r;
}
__device__ __forceinline__ float bflo(u32 u) { return __uint_as_float(u << 16); }
__device__ __forceinline__ float bfhi(u32 u) { return __uint_as_float(u & 0xFFFF0000u); }

__device__ __forceinline__ void gload16(const u16* g, u16* l) {
    __builtin_amdgcn_global_load_lds(
        (const __attribute__((address_space(1))) void*)g,
        (__attribute__((address_space(3))) void*)l, 16, 0, 0);
}

// ---------------- CSR build ----------------
__global__ void k_count(const int* __restrict__ col, int* __restrict__ cnt, int E) {
    int e = blockIdx.x * blockDim.x + threadIdx.x;
    if (e < E) atomicAdd(&cnt[col[e]], 1);
}

__global__ void k_exscan(const int* __restrict__ cnt, int* __restrict__ rp, int n) {
    __shared__ int sm[256];
    int tid = threadIdx.x;
    int chunk = (n + 255) >> 8;
    int b = tid * chunk;
    int e = b + chunk; if (e > n) e = n; if (b > n) b = n;
    int s = 0;
    for (int i = b; i < e; ++i) s += cnt[i];
    sm[tid] = s;
    __syncthreads();
    if (tid == 0) {
        int run = 0;
        for (int i = 0; i < 256; ++i) { int v = sm[i]; sm[i] = run; run += v; }
    }
    __syncthreads();
    int off = sm[tid];
    for (int i = b; i < e; ++i) { rp[i] = off; off += cnt[i]; }
    if (tid == 255) rp[n] = off;
}

__global__ void k_fill(const int* __restrict__ row, const int* __restrict__ col,
                       const int* __restrict__ rp, int* __restrict__ cur,
                       int* __restrict__ src, int E) {
    int e = blockIdx.x * blockDim.x + threadIdx.x;
    if (e >= E) return;
    int c = col[e];
    int pos = rp[c] + atomicAdd(&cur[c], 1);
    src[pos] = row[e];
}

__global__ void k_dinv(const int* __restrict__ rp, float* __restrict__ dinv, int n) {
    int v = blockIdx.x * blockDim.x + threadIdx.x;
    if (v < n) dinv[v] = rsqrtf((float)(rp[v + 1] - rp[v] + 1));  // +1 self-loop
}

// ---------------- weight transpose + bf16 cast: W[K][N] f32 -> Wt[N][K] bf16 ----------------
__global__ void k_wt(const float* __restrict__ W, u16* __restrict__ Wt, int K, int N) {
    __shared__ u16 sm[32][33];
    const float* Wl = W + (size_t)blockIdx.z * K * N;
    u16* Wtl = Wt + (size_t)blockIdx.z * K * N;
    int k0 = blockIdx.y * 32, n0 = blockIdx.x * 32;
    int tx = threadIdx.x, ty = threadIdx.y;  // 32 x 8
#pragma unroll
    for (int r = 0; r < 32; r += 8)
        sm[ty + r][tx] = f2bf(Wl[(size_t)(k0 + ty + r) * N + n0 + tx]);
    __syncthreads();
#pragma unroll
    for (int r = 0; r < 32; r += 8)
        Wtl[(size_t)(n0 + ty + r) * K + k0 + tx] = sm[tx][ty + r];
}

// ---------------- fp32 -> bf16 cast (x) ----------------
__global__ void k_xcast(const float* __restrict__ x, u16* __restrict__ xb, int n4) {
    int i = blockIdx.x * blockDim.x + threadIdx.x;
    if (i >= n4) return;
    float4 v = ((const float4*)x)[i];
    ushort4 o;
    o.x = f2bf(v.x); o.y = f2bf(v.y); o.z = f2bf(v.z); o.w = f2bf(v.w);
    *(ushort4*)(xb + ((size_t)i << 2)) = o;
}

// ---------------- bf16 MFMA GEMM: C[M][Nc] = A[M][K] @ Bt[Nc][K]^T + bias, bf16 out ----------------
// m97 structure: 128x128 tile, 4 waves, each 4x4 of 16x16x32 MFMA, global_load_lds(16B)
__global__ __launch_bounds__(256) void k_gemm_bf16(const u16* __restrict__ A,
                                                   const u16* __restrict__ Bt,
                                                   const float* __restrict__ bias,
                                                   u16* __restrict__ C,
                                                   int M, int Nc, int K) {
    __shared__ u16 As[128 * 32];
    __shared__ u16 Bs[128 * 32];
    const int tid = threadIdx.x;
    const int w = tid >> 6, lane = tid & 63;
    const int m0 = blockIdx.x * 128;
    const int n0 = blockIdx.y * 128;
    const int wr = (w >> 1) * 64, wc = (w & 1) * 64;
    const int lm = lane & 15, lq = lane >> 4;

    f32x4 acc[4][4];
#pragma unroll
    for (int i = 0; i < 4; ++i)
#pragma unroll
        for (int j = 0; j < 4; ++j) acc[i][j] = (f32x4){0.f, 0.f, 0.f, 0.f};

    const int srow = w * 16 + (lane >> 2);   // + l*64 per issue
    const int scol = (lane & 3) * 8;

    for (int k0 = 0; k0 < K; k0 += 32) {
        // A tile: rows m0..m0+127, k0..k0+31, row-major [128][32]
        int gm = m0 + srow;        if (gm >= M) gm = M - 1;
        gload16(A + (size_t)gm * K + k0 + scol, As + (size_t)(w * 64) * 8);
        int gm2 = m0 + 64 + srow;  if (gm2 >= M) gm2 = M - 1;
        gload16(A + (size_t)gm2 * K + k0 + scol, As + (size_t)(256 + w * 64) * 8);
        // B tile: Bt rows n0..n0+127 (always in-bounds, Nc multiple of 128)
        gload16(Bt + (size_t)(n0 + srow) * K + k0 + scol, Bs + (size_t)(w * 64) * 8);
        gload16(Bt + (size_t)(n0 + 64 + srow) * K + k0 + scol, Bs + (size_t)(256 + w * 64) * 8);
        __syncthreads();

        bf16x8 af[4], bf[4];
#pragma unroll
        for (int i = 0; i < 4; ++i)
            af[i] = *(const bf16x8*)(As + (wr + i * 16 + lm) * 32 + lq * 8);
#pragma unroll
        for (int j = 0; j < 4; ++j)
            bf[j] = *(const bf16x8*)(Bs + (wc + j * 16 + lm) * 32 + lq * 8);
#pragma unroll
        for (int i = 0; i < 4; ++i)
#pragma unroll
            for (int j = 0; j < 4; ++j)
                acc[i][j] = __builtin_amdgcn_mfma_f32_16x16x32_bf16(af[i], bf[j], acc[i][j], 0, 0, 0);
        __syncthreads();
    }

    // epilogue: C/D layout col=lane&15, row=(lane>>4)*4+reg  [m89-verified]
#pragma unroll
    for (int j = 0; j < 4; ++j) {
        int gc = n0 + wc + j * 16 + lm;
        float bj = bias[gc];
#pragma unroll
        for (int i = 0; i < 4; ++i) {
#pragma unroll
            for (int r = 0; r < 4; ++r) {
                int gr = m0 + wr + i * 16 + lq * 4 + r;
                if (gr < M) C[(size_t)gr * Nc + gc] = f2bf(acc[i][j][r] + bj);
            }
        }
    }
}

// ---------------- fp32 tiled GEMM (kept for out_fc): C = A@B + bias ----------------
#define BM 128
#define BN 128
#define BK 16
__global__ __launch_bounds__(256) void k_gemm(const float* __restrict__ A,
                                              const float* __restrict__ B,
                                              const float* __restrict__ bias,
                                              float* __restrict__ C,
                                              int M, int Nc, int K) {
    __shared__ float Asm[BK][BM + 4];
    __shared__ float Bsm[BK][BN + 4];
    const int m0 = blockIdx.x * BM;
    const int n0 = blockIdx.y * BN;
    const int tid = threadIdx.x;
    const int tx = tid & 15;
    const int ty = tid >> 4;
    float acc[8][8];
#pragma unroll
    for (int i = 0; i < 8; ++i)
#pragma unroll
        for (int j = 0; j < 8; ++j) acc[i][j] = 0.f;

    for (int k0 = 0; k0 < K; k0 += BK) {
#pragma unroll
        for (int l = 0; l < 2; ++l) {
            int idx = tid + l * 256;
            int r = idx >> 2, c4 = (idx & 3) << 2;
            int gm = m0 + r;
            float4 v = make_float4(0.f, 0.f, 0.f, 0.f);
            if (gm < M) v = *(const float4*)(A + (size_t)gm * K + k0 + c4);
            Asm[c4 + 0][r] = v.x; Asm[c4 + 1][r] = v.y;
            Asm[c4 + 2][r] = v.z; Asm[c4 + 3][r] = v.w;
        }
#pragma unroll
        for (int l = 0; l < 2; ++l) {
            int idx = tid + l * 256;
            int r = idx >> 5, c4 = (idx & 31) << 2;
            int gn = n0 + c4;
            float4 v = make_float4(0.f, 0.f, 0.f, 0.f);
            if (gn < Nc) v = *(const float4*)(B + (size_t)(k0 + r) * Nc + gn);
            *(float4*)&Bsm[r][c4] = v;
        }
        __syncthreads();
#pragma unroll
        for (int k = 0; k < BK; ++k) {
            float a[8], b[8];
            *(float4*)&a[0] = *(const float4*)&Asm[k][ty * 8];
            *(float4*)&a[4] = *(const float4*)&Asm[k][ty * 8 + 4];
            *(float4*)&b[0] = *(const float4*)&Bsm[k][tx * 8];
            *(float4*)&b[4] = *(const float4*)&Bsm[k][tx * 8 + 4];
#pragma unroll
            for (int i = 0; i < 8; ++i)
#pragma unroll
                for (int j = 0; j < 8; ++j)
                    acc[i][j] = fmaf(a[i], b[j], acc[i][j]);
        }
        __syncthreads();
    }
#pragma unroll
    for (int i = 0; i < 8; ++i) {
        int gm = m0 + ty * 8 + i;
        if (gm >= M) continue;
#pragma unroll
        for (int j = 0; j < 8; j += 4) {
            int gn = n0 + tx * 8 + j;
            if (gn < Nc) {
                float4 v;
                v.x = acc[i][j + 0] + bias[gn + 0];
                v.y = acc[i][j + 1] + bias[gn + 1];
                v.z = acc[i][j + 2] + bias[gn + 2];
                v.w = acc[i][j + 3] + bias[gn + 3];
                *(float4*)(C + (size_t)gm * Nc + gn) = v;
            }
        }
    }
}

// ---------------- gather SpMM over bf16 t -> fp32 h ----------------
__global__ __launch_bounds__(256) void k_spmm_bf16(const u16* __restrict__ t,
                                                   const int* __restrict__ rp,
                                                   const int* __restrict__ src,
                                                   const float* __restrict__ dinv,
                                                   float* __restrict__ h) {
    int gt = blockIdx.x * blockDim.x + threadIdx.x;
    int v = gt >> 6;            // one wave per node
    int lane = threadIdx.x & 63;
    if (v >= NN) return;
    int c = lane << 2;          // 4 cols per lane
    float dv = dinv[v];
    uint2 a = *(const uint2*)(t + (size_t)v * HH + c);
    float w0 = dv * dv;
    float4 accv;
    accv.x = bflo(a.x) * w0; accv.y = bfhi(a.x) * w0;
    accv.z = bflo(a.y) * w0; accv.w = bfhi(a.y) * w0;
    int beg = rp[v], end = rp[v + 1];
    for (int j = beg; j < end; ++j) {
        int s = src[j];                       // wave-uniform
        float w = dinv[s] * dv;
        uint2 b = *(const uint2*)(t + (size_t)s * HH + c);
        accv.x = fmaf(bflo(b.x), w, accv.x);
        accv.y = fmaf(bfhi(b.x), w, accv.y);
        accv.z = fmaf(bflo(b.y), w, accv.z);
        accv.w = fmaf(bfhi(b.y), w, accv.w);
    }
    *(float4*)(h + (size_t)v * HH + c) = accv;
}

// ---------------- BatchNorm stats ----------------
#define RPB 128
__global__ void k_bnstats(const float* __restrict__ h, float* __restrict__ s,
                          float* __restrict__ q) {
    int col = threadIdx.x;       // 256 threads == H columns
    int r0 = blockIdx.x * RPB;
    int r1 = r0 + RPB; if (r1 > NN) r1 = NN;
    float sum = 0.f, sq = 0.f;
    for (int r = r0; r < r1; ++r) {
        float v = h[(size_t)r * HH + col];
        sum += v;
        sq = fmaf(v, v, sq);
    }
    atomicAdd(&s[col], sum);
    atomicAdd(&q[col], sq);
}

// ---------------- normalize + ReLU + weighted residual; writes bf16 h ----------------
__global__ void k_bnnorm(const float* __restrict__ hraw, float* __restrict__ acc,
                         u16* __restrict__ hb,
                         const float* __restrict__ s, const float* __restrict__ q,
                         const float* __restrict__ gamma, const float* __restrict__ beta,
                         const float* __restrict__ wArr, int layer) {
    int idx = blockIdx.x * blockDim.x + threadIdx.x;
    if (idx >= NN * (HH / 4)) return;
    int c = (idx & 63) << 2;
    const float invN = 1.0f / (float)NN;
    float w = wArr[layer];
    float4 hv = ((const float4*)hraw)[idx];
    float4 av = ((const float4*)acc)[idx];
    float* hp = &hv.x;
    float* ap = &av.x;
    ushort4 o;
    u16* op = &o.x;
#pragma unroll
    for (int k = 0; k < 4; ++k) {
        float mu = s[c + k] * invN;
        float var = q[c + k] * invN - mu * mu;
        float g = gamma[layer * HH + c + k];
        float b = beta[layer * HH + c + k];
        float v = (hp[k] - mu) * rsqrtf(var + EPSB) * g + b;
        v = fmaxf(v, 0.f);
        ap[k] = fmaf(w, v, ap[k]);
        op[k] = f2bf(v);
    }
    ((float4*)acc)[idx] = av;
    *(ushort4*)(hb + ((size_t)idx << 2)) = o;
}

// ---------------- softmax of the 8 layer weights ----------------
__global__ void k_softmaxw(const float* __restrict__ lw, float* __restrict__ wArr) {
    if (threadIdx.x == 0 && blockIdx.x == 0) {
        float m = -3.0e38f;
        for (int i = 0; i < LL; ++i) m = fmaxf(m, lw[i]);
        float e[LL]; float sum = 0.f;
        for (int i = 0; i < LL; ++i) { e[i] = expf(lw[i] - m); sum += e[i]; }
        for (int i = 0; i < LL; ++i) wArr[i] = e[i] / sum;
    }
}

// ---------------- log_softmax rows ----------------
__global__ __launch_bounds__(256) void k_logsoftmax(const float* __restrict__ z,
                                                    float* __restrict__ out) {
    int gt = blockIdx.x * blockDim.x + threadIdx.x;
    int v = gt >> 6;
    int lane = threadIdx.x & 63;
    if (v >= NN) return;
    const float* row = z + (size_t)v * CC;
    float v0 = row[lane];
    float v1 = (lane + 64 < CC) ? row[lane + 64] : -3.0e38f;
    float m = fmaxf(v0, v1);
#pragma unroll
    for (int d = 1; d < 64; d <<= 1) m = fmaxf(m, __shfl_xor(m, d, 64));
    float e = expf(v0 - m) + ((lane + 64 < CC) ? expf(v1 - m) : 0.f);
#pragma unroll
    for (int d = 1; d < 64; d <<= 1) e += __shfl_xor(e, d, 64);
    float lse = m + logf(e);
    out[(size_t)v * CC + lane] = v0 - lse;
    if (lane + 64 < CC) out[(size_t)v * CC + lane + 64] = v1 - lse;
}

extern "C" void kernel_launch(void* const* d_in, const int* in_sizes, int n_in,
                              void* d_out, int out_size, void* d_ws, size_t ws_size,
                              hipStream_t stream) {
    const float* x     = (const float*)d_in[0];
    const int*   e1    = (const int*)d_in[1];
    const int*   e2    = (const int*)d_in[2];
    const float* inW   = (const float*)d_in[3];
    const float* inb   = (const float*)d_in[4];
    const float* convW = (const float*)d_in[5];
    const float* convB = (const float*)d_in[6];
    const float* gamma = (const float*)d_in[7];
    const float* beta  = (const float*)d_in[8];
    const float* outW  = (const float*)d_in[9];
    const float* outb  = (const float*)d_in[10];
    const float* lw    = (const float*)d_in[11];

    char* ws = (char*)d_ws;
    size_t off = 0;
    auto alloc = [&](size_t bytes) -> void* {
        void* p = ws + off;
        off = (off + bytes + 255) & ~(size_t)255;
        return p;
    };
    u16*   hb    = (u16*)alloc((size_t)NN * HH * 2);     // bf16 h (GEMM A)
    u16*   tb    = (u16*)alloc((size_t)NN * HH * 2);     // bf16 t (GEMM out / spmm in)
    float* hraw  = (float*)alloc((size_t)NN * HH * 4);   // fp32 spmm out; reused as logits
    float* acc   = (float*)alloc((size_t)NN * HH * 4);
    u16*   convWt= (u16*)alloc((size_t)LL * HH * HH * 2);
    u16*   inWt  = (u16*)alloc((size_t)HH * FIN * 2);
    float* dinv1 = (float*)alloc((size_t)NN * 4);
    float* dinv2 = (float*)alloc((size_t)NN * 4);
    int*   rp1   = (int*)alloc((size_t)(NN + 1) * 4);
    int*   rp2   = (int*)alloc((size_t)(NN + 1) * 4);
    int*   src1  = (int*)alloc((size_t)EE * 4);
    int*   src2  = (int*)alloc((size_t)EE * 4);
    int*   cnt   = (int*)alloc((size_t)NN * 4);
    float* bns   = (float*)alloc(HH * 4);
    float* bnq   = (float*)alloc(HH * 4);
    float* wArr  = (float*)alloc(64);
    u16*   xb    = tb;   // alias: x_bf16 only needed before layer-0 GEMM writes tb
    float* logits = hraw;

    const int EB = (EE + 255) / 256;
    const int NB = (NN + 255) / 256;

    // CSR for adjacency 1
    hipMemsetAsync(cnt, 0, (size_t)NN * 4, stream);
    k_count<<<EB, 256, 0, stream>>>(e1 + EE, cnt, EE);
    k_exscan<<<1, 256, 0, stream>>>(cnt, rp1, NN);
    hipMemsetAsync(cnt, 0, (size_t)NN * 4, stream);
    k_fill<<<EB, 256, 0, stream>>>(e1, e1 + EE, rp1, cnt, src1, EE);
    k_dinv<<<NB, 256, 0, stream>>>(rp1, dinv1, NN);

    // CSR for adjacency 2
    hipMemsetAsync(cnt, 0, (size_t)NN * 4, stream);
    k_count<<<EB, 256, 0, stream>>>(e2 + EE, cnt, EE);
    k_exscan<<<1, 256, 0, stream>>>(cnt, rp2, NN);
    hipMemsetAsync(cnt, 0, (size_t)NN * 4, stream);
    k_fill<<<EB, 256, 0, stream>>>(e2, e2 + EE, rp2, cnt, src2, EE);
    k_dinv<<<NB, 256, 0, stream>>>(rp2, dinv2, NN);

    k_softmaxw<<<1, 64, 0, stream>>>(lw, wArr);

    // weight prep: convW [L][H][H] -> convWt [L][H][H] (n-major), inW [FIN][H] -> inWt [H][FIN]
    {
        dim3 g(HH / 32, HH / 32, LL);
        dim3 b(32, 8);
        k_wt<<<g, b, 0, stream>>>(convW, convWt, HH, HH);
        dim3 g2(HH / 32, FIN / 32, 1);
        k_wt<<<g2, b, 0, stream>>>(inW, inWt, FIN, HH);
    }
    k_xcast<<<(NN * FIN / 4 + 255) / 256, 256, 0, stream>>>(x, xb, NN * FIN / 4);

    const int MT = (NN + 127) / 128;  // 391
    // input FC: hb = bf16( x @ inW + inb )
    {
        dim3 g(MT, HH / 128);
        k_gemm_bf16<<<g, 256, 0, stream>>>(xb, inWt, inb, hb, NN, HH, FIN);
    }

    hipMemsetAsync(acc, 0, (size_t)NN * HH * 4, stream);

    const int SPB = (NN * 64 + 255) / 256;
    const int ELB = (NN * (HH / 4) + 255) / 256;
    for (int i = 0; i < LL; ++i) {
        dim3 g(MT, HH / 128);
        k_gemm_bf16<<<g, 256, 0, stream>>>(hb, convWt + (size_t)i * HH * HH,
                                           convB + (size_t)i * HH, tb, NN, HH, HH);
        const int* rp = (i < LL / 2) ? rp1 : rp2;
        const int* sr = (i < LL / 2) ? src1 : src2;
        const float* dv = (i < LL / 2) ? dinv1 : dinv2;
        k_spmm_bf16<<<SPB, 256, 0, stream>>>(tb, rp, sr, dv, hraw);
        hipMemsetAsync(bns, 0, HH * 4, stream);
        hipMemsetAsync(bnq, 0, HH * 4, stream);
        k_bnstats<<<(NN + RPB - 1) / RPB, 256, 0, stream>>>(hraw, bns, bnq);
        k_bnnorm<<<ELB, 256, 0, stream>>>(hraw, acc, hb, bns, bnq, gamma, beta, wArr, i);
    }

    // out FC (fp32 for accuracy): logits = acc @ outW + outb
    {
        dim3 g(MT, 1);
        k_gemm<<<g, 256, 0, stream>>>(acc, outW, outb, logits, NN, CC, HH);
    }
    k_logsoftmax<<<SPB, 256, 0, stream>>>(logits, (float*)d_out);
}

// Round 3
// 1895.264 us; speedup vs baseline: 1.5940x; 1.2325x over previous
//
#include <hip/hip_runtime.h>
#include <math.h>

#define NN 50000
#define HH 256
#define FIN 128
#define CC 112
#define LL 8
#define EE 800000
#define EPSB 1e-5f

typedef unsigned short u16;
typedef unsigned int u32;
typedef __attribute__((ext_vector_type(8))) short bf16x8;
typedef __attribute__((ext_vector_type(4))) float f32x4;

__device__ __forceinline__ u16 f2bf(float f) {
    u32 u = __float_as_uint(f);
    u32 r = (u + 0x7FFFu + ((u >> 16) & 1u)) >> 16;   // RNE
    return (u16)r;
}
__device__ __forceinline__ float bflo(u32 u) { return __uint_as_float(u << 16); }
__device__ __forceinline__ float bfhi(u32 u) { return __uint_as_float(u & 0xFFFF0000u); }

__device__ __forceinline__ void gload16(const u16* g, u16* l) {
    __builtin_amdgcn_global_load_lds(
        (const __attribute__((address_space(1))) void*)g,
        (__attribute__((address_space(3))) void*)l, 16, 0, 0);
}

// ---------------- CSR build ----------------
__global__ void k_count(const int* __restrict__ col, int* __restrict__ cnt, int E) {
    int e = blockIdx.x * blockDim.x + threadIdx.x;
    if (e < E) atomicAdd(&cnt[col[e]], 1);
}

__global__ void k_exscan(const int* __restrict__ cnt, int* __restrict__ rp, int n) {
    __shared__ int sm[256];
    int tid = threadIdx.x;
    int chunk = (n + 255) >> 8;
    int b = tid * chunk;
    int e = b + chunk; if (e > n) e = n; if (b > n) b = n;
    int s = 0;
    for (int i = b; i < e; ++i) s += cnt[i];
    sm[tid] = s;
    __syncthreads();
    if (tid == 0) {
        int run = 0;
        for (int i = 0; i < 256; ++i) { int v = sm[i]; sm[i] = run; run += v; }
    }
    __syncthreads();
    int off = sm[tid];
    for (int i = b; i < e; ++i) { rp[i] = off; off += cnt[i]; }
    if (tid == 255) rp[n] = off;
}

__global__ void k_fill(const int* __restrict__ row, const int* __restrict__ col,
                       const int* __restrict__ rp, int* __restrict__ cur,
                       int* __restrict__ src, int E) {
    int e = blockIdx.x * blockDim.x + threadIdx.x;
    if (e >= E) return;
    int c = col[e];
    int pos = rp[c] + atomicAdd(&cur[c], 1);
    src[pos] = row[e];
}

__global__ void k_dinv(const int* __restrict__ rp, float* __restrict__ dinv, int n) {
    int v = blockIdx.x * blockDim.x + threadIdx.x;
    if (v < n) dinv[v] = rsqrtf((float)(rp[v + 1] - rp[v] + 1));  // +1 self-loop
}

// ---------------- weight transpose + bf16 cast: W[K][N] f32 -> Wt[N][K] bf16 ----------------
__global__ void k_wt(const float* __restrict__ W, u16* __restrict__ Wt, int K, int N) {
    __shared__ u16 sm[32][33];
    const float* Wl = W + (size_t)blockIdx.z * K * N;
    u16* Wtl = Wt + (size_t)blockIdx.z * K * N;
    int k0 = blockIdx.y * 32, n0 = blockIdx.x * 32;
    int tx = threadIdx.x, ty = threadIdx.y;  // 32 x 8
#pragma unroll
    for (int r = 0; r < 32; r += 8)
        sm[ty + r][tx] = f2bf(Wl[(size_t)(k0 + ty + r) * N + n0 + tx]);
    __syncthreads();
#pragma unroll
    for (int r = 0; r < 32; r += 8)
        Wtl[(size_t)(n0 + ty + r) * K + k0 + tx] = sm[tx][ty + r];
}

// ---------------- fp32 -> bf16 cast (x) ----------------
__global__ void k_xcast(const float* __restrict__ x, u16* __restrict__ xb, int n4) {
    int i = blockIdx.x * blockDim.x + threadIdx.x;
    if (i >= n4) return;
    float4 v = ((const float4*)x)[i];
    ushort4 o;
    o.x = f2bf(v.x); o.y = f2bf(v.y); o.z = f2bf(v.z); o.w = f2bf(v.w);
    *(ushort4*)(xb + ((size_t)i << 2)) = o;
}

// ---------------- bf16 MFMA GEMM: C = A @ Bt^T + bias, optional per-row scale, bf16 out ----
__global__ __launch_bounds__(256) void k_gemm_bf16(const u16* __restrict__ A,
                                                   const u16* __restrict__ Bt,
                                                   const float* __restrict__ bias,
                                                   const float* __restrict__ rowscale,
                                                   u16* __restrict__ C,
                                                   int M, int Nc, int K) {
    __shared__ u16 As[128 * 32];
    __shared__ u16 Bs[128 * 32];
    const int tid = threadIdx.x;
    const int w = tid >> 6, lane = tid & 63;
    const int m0 = blockIdx.x * 128;
    const int n0 = blockIdx.y * 128;
    const int wr = (w >> 1) * 64, wc = (w & 1) * 64;
    const int lm = lane & 15, lq = lane >> 4;

    f32x4 acc[4][4];
#pragma unroll
    for (int i = 0; i < 4; ++i)
#pragma unroll
        for (int j = 0; j < 4; ++j) acc[i][j] = (f32x4){0.f, 0.f, 0.f, 0.f};

    const int srow = w * 16 + (lane >> 2);
    const int scol = (lane & 3) * 8;

    for (int k0 = 0; k0 < K; k0 += 32) {
        int gm = m0 + srow;        if (gm >= M) gm = M - 1;
        gload16(A + (size_t)gm * K + k0 + scol, As + (size_t)(w * 64) * 8);
        int gm2 = m0 + 64 + srow;  if (gm2 >= M) gm2 = M - 1;
        gload16(A + (size_t)gm2 * K + k0 + scol, As + (size_t)(256 + w * 64) * 8);
        gload16(Bt + (size_t)(n0 + srow) * K + k0 + scol, Bs + (size_t)(w * 64) * 8);
        gload16(Bt + (size_t)(n0 + 64 + srow) * K + k0 + scol, Bs + (size_t)(256 + w * 64) * 8);
        __syncthreads();

        bf16x8 af[4], bfr[4];
#pragma unroll
        for (int i = 0; i < 4; ++i)
            af[i] = *(const bf16x8*)(As + (wr + i * 16 + lm) * 32 + lq * 8);
#pragma unroll
        for (int j = 0; j < 4; ++j)
            bfr[j] = *(const bf16x8*)(Bs + (wc + j * 16 + lm) * 32 + lq * 8);
#pragma unroll
        for (int i = 0; i < 4; ++i)
#pragma unroll
            for (int j = 0; j < 4; ++j)
                acc[i][j] = __builtin_amdgcn_mfma_f32_16x16x32_bf16(af[i], bfr[j], acc[i][j], 0, 0, 0);
        __syncthreads();
    }

    // epilogue: C/D layout col=lane&15, row=(lane>>4)*4+reg  [m89-verified]
#pragma unroll
    for (int j = 0; j < 4; ++j) {
        int gc = n0 + wc + j * 16 + lm;
        float bj = bias[gc];
#pragma unroll
        for (int i = 0; i < 4; ++i) {
#pragma unroll
            for (int r = 0; r < 4; ++r) {
                int gr = m0 + wr + i * 16 + lq * 4 + r;
                if (gr < M) {
                    float rs = rowscale ? rowscale[gr] : 1.0f;
                    C[(size_t)gr * Nc + gc] = f2bf((acc[i][j][r] + bj) * rs);
                }
            }
        }
    }
}

// ---------------- fp32 tiled GEMM (out_fc): C = A@B + bias ----------------
#define BM 128
#define BN 128
#define BK 16
__global__ __launch_bounds__(256) void k_gemm(const float* __restrict__ A,
                                              const float* __restrict__ B,
                                              const float* __restrict__ bias,
                                              float* __restrict__ C,
                                              int M, int Nc, int K) {
    __shared__ float Asm[BK][BM + 4];
    __shared__ float Bsm[BK][BN + 4];
    const int m0 = blockIdx.x * BM;
    const int n0 = blockIdx.y * BN;
    const int tid = threadIdx.x;
    const int tx = tid & 15;
    const int ty = tid >> 4;
    float acc[8][8];
#pragma unroll
    for (int i = 0; i < 8; ++i)
#pragma unroll
        for (int j = 0; j < 8; ++j) acc[i][j] = 0.f;

    for (int k0 = 0; k0 < K; k0 += BK) {
#pragma unroll
        for (int l = 0; l < 2; ++l) {
            int idx = tid + l * 256;
            int r = idx >> 2, c4 = (idx & 3) << 2;
            int gm = m0 + r;
            float4 v = make_float4(0.f, 0.f, 0.f, 0.f);
            if (gm < M) v = *(const float4*)(A + (size_t)gm * K + k0 + c4);
            Asm[c4 + 0][r] = v.x; Asm[c4 + 1][r] = v.y;
            Asm[c4 + 2][r] = v.z; Asm[c4 + 3][r] = v.w;
        }
#pragma unroll
        for (int l = 0; l < 2; ++l) {
            int idx = tid + l * 256;
            int r = idx >> 5, c4 = (idx & 31) << 2;
            int gn = n0 + c4;
            float4 v = make_float4(0.f, 0.f, 0.f, 0.f);
            if (gn < Nc) v = *(const float4*)(B + (size_t)(k0 + r) * Nc + gn);
            *(float4*)&Bsm[r][c4] = v;
        }
        __syncthreads();
#pragma unroll
        for (int k = 0; k < BK; ++k) {
            float a[8], b[8];
            *(float4*)&a[0] = *(const float4*)&Asm[k][ty * 8];
            *(float4*)&a[4] = *(const float4*)&Asm[k][ty * 8 + 4];
            *(float4*)&b[0] = *(const float4*)&Bsm[k][tx * 8];
            *(float4*)&b[4] = *(const float4*)&Bsm[k][tx * 8 + 4];
#pragma unroll
            for (int i = 0; i < 8; ++i)
#pragma unroll
                for (int j = 0; j < 8; ++j)
                    acc[i][j] = fmaf(a[i], b[j], acc[i][j]);
        }
        __syncthreads();
    }
#pragma unroll
    for (int i = 0; i < 8; ++i) {
        int gm = m0 + ty * 8 + i;
        if (gm >= M) continue;
#pragma unroll
        for (int j = 0; j < 8; j += 4) {
            int gn = n0 + tx * 8 + j;
            if (gn < Nc) {
                float4 v;
                v.x = acc[i][j + 0] + bias[gn + 0];
                v.y = acc[i][j + 1] + bias[gn + 1];
                v.z = acc[i][j + 2] + bias[gn + 2];
                v.w = acc[i][j + 3] + bias[gn + 3];
                *(float4*)(C + (size_t)gm * Nc + gn) = v;
            }
        }
    }
}

// ---------------- gather SpMM, premultiplied t' = dinv[r]*t[r] (bf16) ----------------
// h[v] = dv * ( t'[v] + sum_edges t'[src] ),  unroll-8 for MLP
__global__ __launch_bounds__(256) void k_spmm_bf16(const u16* __restrict__ t,
                                                   const int* __restrict__ rp,
                                                   const int* __restrict__ src,
                                                   const float* __restrict__ dinv,
                                                   float* __restrict__ h) {
    int gt = blockIdx.x * blockDim.x + threadIdx.x;
    int v = gt >> 6;            // one wave per node
    int lane = threadIdx.x & 63;
    if (v >= NN) return;
    int c = lane << 2;          // 4 cols per lane
    const u16* tp = t + c;
    float dv = dinv[v];
    uint2 a = *(const uint2*)(tp + (size_t)v * HH);
    float4 accv;
    accv.x = bflo(a.x); accv.y = bfhi(a.x);
    accv.z = bflo(a.y); accv.w = bfhi(a.y);
    int beg = rp[v], end = rp[v + 1];
    int j = beg;
    for (; j + 8 <= end; j += 8) {
        int s0 = src[j + 0], s1 = src[j + 1], s2 = src[j + 2], s3 = src[j + 3];
        int s4 = src[j + 4], s5 = src[j + 5], s6 = src[j + 6], s7 = src[j + 7];
        uint2 b0 = *(const uint2*)(tp + (size_t)s0 * HH);
        uint2 b1 = *(const uint2*)(tp + (size_t)s1 * HH);
        uint2 b2 = *(const uint2*)(tp + (size_t)s2 * HH);
        uint2 b3 = *(const uint2*)(tp + (size_t)s3 * HH);
        uint2 b4 = *(const uint2*)(tp + (size_t)s4 * HH);
        uint2 b5 = *(const uint2*)(tp + (size_t)s5 * HH);
        uint2 b6 = *(const uint2*)(tp + (size_t)s6 * HH);
        uint2 b7 = *(const uint2*)(tp + (size_t)s7 * HH);
        accv.x += bflo(b0.x) + bflo(b1.x) + bflo(b2.x) + bflo(b3.x)
                + bflo(b4.x) + bflo(b5.x) + bflo(b6.x) + bflo(b7.x);
        accv.y += bfhi(b0.x) + bfhi(b1.x) + bfhi(b2.x) + bfhi(b3.x)
                + bfhi(b4.x) + bfhi(b5.x) + bfhi(b6.x) + bfhi(b7.x);
        accv.z += bflo(b0.y) + bflo(b1.y) + bflo(b2.y) + bflo(b3.y)
                + bflo(b4.y) + bflo(b5.y) + bflo(b6.y) + bflo(b7.y);
        accv.w += bfhi(b0.y) + bfhi(b1.y) + bfhi(b2.y) + bfhi(b3.y)
                + bfhi(b4.y) + bfhi(b5.y) + bfhi(b6.y) + bfhi(b7.y);
    }
    for (; j + 2 <= end; j += 2) {
        int s0 = src[j], s1 = src[j + 1];
        uint2 b0 = *(const uint2*)(tp + (size_t)s0 * HH);
        uint2 b1 = *(const uint2*)(tp + (size_t)s1 * HH);
        accv.x += bflo(b0.x) + bflo(b1.x);
        accv.y += bfhi(b0.x) + bfhi(b1.x);
        accv.z += bflo(b0.y) + bflo(b1.y);
        accv.w += bfhi(b0.y) + bfhi(b1.y);
    }
    if (j < end) {
        int s0 = src[j];
        uint2 b0 = *(const uint2*)(tp + (size_t)s0 * HH);
        accv.x += bflo(b0.x); accv.y += bfhi(b0.x);
        accv.z += bflo(b0.y); accv.w += bfhi(b0.y);
    }
    accv.x *= dv; accv.y *= dv; accv.z *= dv; accv.w *= dv;
    *(float4*)(h + (size_t)v * HH + c) = accv;
}

// ---------------- BatchNorm stats ----------------
#define RPB 128
__global__ void k_bnstats(const float* __restrict__ h, float* __restrict__ s,
                          float* __restrict__ q) {
    int col = threadIdx.x;       // 256 threads == H columns
    int r0 = blockIdx.x * RPB;
    int r1 = r0 + RPB; if (r1 > NN) r1 = NN;
    float sum = 0.f, sq = 0.f;
    for (int r = r0; r < r1; ++r) {
        float v = h[(size_t)r * HH + col];
        sum += v;
        sq = fmaf(v, v, sq);
    }
    atomicAdd(&s[col], sum);
    atomicAdd(&q[col], sq);
}

// ---------------- normalize + ReLU + weighted residual; writes bf16 h ----------------
__global__ void k_bnnorm(const float* __restrict__ hraw, float* __restrict__ acc,
                         u16* __restrict__ hb,
                         const float* __restrict__ s, const float* __restrict__ q,
                         const float* __restrict__ gamma, const float* __restrict__ beta,
                         const float* __restrict__ wArr, int layer) {
    int idx = blockIdx.x * blockDim.x + threadIdx.x;
    if (idx >= NN * (HH / 4)) return;
    int c = (idx & 63) << 2;
    const float invN = 1.0f / (float)NN;
    float w = wArr[layer];
    float4 hv = ((const float4*)hraw)[idx];
    float4 av = ((const float4*)acc)[idx];
    float* hp = &hv.x;
    float* ap = &av.x;
    ushort4 o;
    u16* op = &o.x;
#pragma unroll
    for (int k = 0; k < 4; ++k) {
        float mu = s[c + k] * invN;
        float var = q[c + k] * invN - mu * mu;
        float g = gamma[layer * HH + c + k];
        float b = beta[layer * HH + c + k];
        float v = (hp[k] - mu) * rsqrtf(var + EPSB) * g + b;
        v = fmaxf(v, 0.f);
        ap[k] = fmaf(w, v, ap[k]);
        op[k] = f2bf(v);
    }
    ((float4*)acc)[idx] = av;
    *(ushort4*)(hb + ((size_t)idx << 2)) = o;
}

// ---------------- softmax of the 8 layer weights ----------------
__global__ void k_softmaxw(const float* __restrict__ lw, float* __restrict__ wArr) {
    if (threadIdx.x == 0 && blockIdx.x == 0) {
        float m = -3.0e38f;
        for (int i = 0; i < LL; ++i) m = fmaxf(m, lw[i]);
        float e[LL]; float sum = 0.f;
        for (int i = 0; i < LL; ++i) { e[i] = expf(lw[i] - m); sum += e[i]; }
        for (int i = 0; i < LL; ++i) wArr[i] = e[i] / sum;
    }
}

// ---------------- log_softmax rows ----------------
__global__ __launch_bounds__(256) void k_logsoftmax(const float* __restrict__ z,
                                                    float* __restrict__ out) {
    int gt = blockIdx.x * blockDim.x + threadIdx.x;
    int v = gt >> 6;
    int lane = threadIdx.x & 63;
    if (v >= NN) return;
    const float* row = z + (size_t)v * CC;
    float v0 = row[lane];
    float v1 = (lane + 64 < CC) ? row[lane + 64] : -3.0e38f;
    float m = fmaxf(v0, v1);
#pragma unroll
    for (int d = 1; d < 64; d <<= 1) m = fmaxf(m, __shfl_xor(m, d, 64));
    float e = expf(v0 - m) + ((lane + 64 < CC) ? expf(v1 - m) : 0.f);
#pragma unroll
    for (int d = 1; d < 64; d <<= 1) e += __shfl_xor(e, d, 64);
    float lse = m + logf(e);
    out[(size_t)v * CC + lane] = v0 - lse;
    if (lane + 64 < CC) out[(size_t)v * CC + lane + 64] = v1 - lse;
}

extern "C" void kernel_launch(void* const* d_in, const int* in_sizes, int n_in,
                              void* d_out, int out_size, void* d_ws, size_t ws_size,
                              hipStream_t stream) {
    const float* x     = (const float*)d_in[0];
    const int*   e1    = (const int*)d_in[1];
    const int*   e2    = (const int*)d_in[2];
    const float* inW   = (const float*)d_in[3];
    const float* inb   = (const float*)d_in[4];
    const float* convW = (const float*)d_in[5];
    const float* convB = (const float*)d_in[6];
    const float* gamma = (const float*)d_in[7];
    const float* beta  = (const float*)d_in[8];
    const float* outW  = (const float*)d_in[9];
    const float* outb  = (const float*)d_in[10];
    const float* lw    = (const float*)d_in[11];

    char* ws = (char*)d_ws;
    size_t off = 0;
    auto alloc = [&](size_t bytes) -> void* {
        void* p = ws + off;
        off = (off + bytes + 255) & ~(size_t)255;
        return p;
    };
    u16*   hb    = (u16*)alloc((size_t)NN * HH * 2);     // bf16 h (GEMM A)
    u16*   tb    = (u16*)alloc((size_t)NN * HH * 2);     // bf16 t' (premultiplied)
    float* hraw  = (float*)alloc((size_t)NN * HH * 4);   // fp32 spmm out; reused as logits
    float* acc   = (float*)alloc((size_t)NN * HH * 4);
    u16*   convWt= (u16*)alloc((size_t)LL * HH * HH * 2);
    u16*   inWt  = (u16*)alloc((size_t)HH * FIN * 2);
    float* dinv1 = (float*)alloc((size_t)NN * 4);
    float* dinv2 = (float*)alloc((size_t)NN * 4);
    int*   rp1   = (int*)alloc((size_t)(NN + 1) * 4);
    int*   rp2   = (int*)alloc((size_t)(NN + 1) * 4);
    int*   src1  = (int*)alloc((size_t)EE * 4);
    int*   src2  = (int*)alloc((size_t)EE * 4);
    int*   cnt   = (int*)alloc((size_t)NN * 4);
    float* bns   = (float*)alloc(HH * 4);
    float* bnq   = (float*)alloc(HH * 4);
    float* wArr  = (float*)alloc(64);
    u16*   xb    = tb;   // alias: x_bf16 only needed before layer-0 GEMM writes tb
    float* logits = hraw;

    const int EB = (EE + 255) / 256;
    const int NB = (NN + 255) / 256;

    // CSR for adjacency 1
    hipMemsetAsync(cnt, 0, (size_t)NN * 4, stream);
    k_count<<<EB, 256, 0, stream>>>(e1 + EE, cnt, EE);
    k_exscan<<<1, 256, 0, stream>>>(cnt, rp1, NN);
    hipMemsetAsync(cnt, 0, (size_t)NN * 4, stream);
    k_fill<<<EB, 256, 0, stream>>>(e1, e1 + EE, rp1, cnt, src1, EE);
    k_dinv<<<NB, 256, 0, stream>>>(rp1, dinv1, NN);

    // CSR for adjacency 2
    hipMemsetAsync(cnt, 0, (size_t)NN * 4, stream);
    k_count<<<EB, 256, 0, stream>>>(e2 + EE, cnt, EE);
    k_exscan<<<1, 256, 0, stream>>>(cnt, rp2, NN);
    hipMemsetAsync(cnt, 0, (size_t)NN * 4, stream);
    k_fill<<<EB, 256, 0, stream>>>(e2, e2 + EE, rp2, cnt, src2, EE);
    k_dinv<<<NB, 256, 0, stream>>>(rp2, dinv2, NN);

    k_softmaxw<<<1, 64, 0, stream>>>(lw, wArr);

    // weight prep
    {
        dim3 g(HH / 32, HH / 32, LL);
        dim3 b(32, 8);
        k_wt<<<g, b, 0, stream>>>(convW, convWt, HH, HH);
        dim3 g2(HH / 32, FIN / 32, 1);
        k_wt<<<g2, b, 0, stream>>>(inW, inWt, FIN, HH);
    }
    k_xcast<<<(NN * FIN / 4 + 255) / 256, 256, 0, stream>>>(x, xb, NN * FIN / 4);

    const int MT = (NN + 127) / 128;  // 391
    // input FC: hb = bf16( x @ inW + inb )   (no row scaling)
    {
        dim3 g(MT, HH / 128);
        k_gemm_bf16<<<g, 256, 0, stream>>>(xb, inWt, inb, nullptr, hb, NN, HH, FIN);
    }

    hipMemsetAsync(acc, 0, (size_t)NN * HH * 4, stream);

    const int SPB = (NN * 64 + 255) / 256;
    const int ELB = (NN * (HH / 4) + 255) / 256;
    for (int i = 0; i < LL; ++i) {
        const int* rp = (i < LL / 2) ? rp1 : rp2;
        const int* sr = (i < LL / 2) ? src1 : src2;
        const float* dv = (i < LL / 2) ? dinv1 : dinv2;
        dim3 g(MT, HH / 128);
        // tb = bf16( dinv[r] * (hb @ convW_i + convB_i) )   -- premultiplied t'
        k_gemm_bf16<<<g, 256, 0, stream>>>(hb, convWt + (size_t)i * HH * HH,
                                           convB + (size_t)i * HH, dv, tb, NN, HH, HH);
        k_spmm_bf16<<<SPB, 256, 0, stream>>>(tb, rp, sr, dv, hraw);
        hipMemsetAsync(bns, 0, HH * 4, stream);
        hipMemsetAsync(bnq, 0, HH * 4, stream);
        k_bnstats<<<(NN + RPB - 1) / RPB, 256, 0, stream>>>(hraw, bns, bnq);
        k_bnnorm<<<ELB, 256, 0, stream>>>(hraw, acc, hb, bns, bnq, gamma, beta, wArr, i);
    }

    // out FC (fp32 for accuracy): logits = acc @ outW + outb
    {
        dim3 g(MT, 1);
        k_gemm<<<g, 256, 0, stream>>>(acc, outW, outb, logits, NN, CC, HH);
    }
    k_logsoftmax<<<SPB, 256, 0, stream>>>(logits, (float*)d_out);
}

// Round 5
// 1636.170 us; speedup vs baseline: 1.8465x; 1.1584x over previous
//
#include <hip/hip_runtime.h>
#include <math.h>

#define NN 50000
#define HH 256
#define FIN 128
#define CC 112
#define LL 8
#define EE 800000
#define EPSB 1e-5f
#define NBLK 196            // ceil(NN/256) for scan

typedef unsigned short u16;
typedef unsigned int u32;
typedef __attribute__((ext_vector_type(8))) short bf16x8;
typedef __attribute__((ext_vector_type(4))) float f32x4;

__device__ __forceinline__ u16 f2bf(float f) {
    u32 u = __float_as_uint(f);
    u32 r = (u + 0x7FFFu + ((u >> 16) & 1u)) >> 16;   // RNE
    return (u16)r;
}
__device__ __forceinline__ float bflo(u32 u) { return __uint_as_float(u << 16); }
__device__ __forceinline__ float bfhi(u32 u) { return __uint_as_float(u & 0xFFFF0000u); }
__device__ __forceinline__ float bf1(u16 u) { return __uint_as_float(((u32)u) << 16); }

__device__ __forceinline__ void gload16(const u16* g, u16* l) {
    __builtin_amdgcn_global_load_lds(
        (const __attribute__((address_space(1))) void*)g,
        (__attribute__((address_space(3))) void*)l, 16, 0, 0);
}

// ---------------- CSR build ----------------
__global__ void k_count(const int* __restrict__ col, int* __restrict__ cnt, int E) {
    int e = blockIdx.x * blockDim.x + threadIdx.x;
    if (e < E) atomicAdd(&cnt[col[e]], 1);
}

__global__ void k_bsum(const int* __restrict__ cnt, int* __restrict__ bsum, int n) {
    __shared__ int sm[256];
    int i = blockIdx.x * 256 + threadIdx.x;
    sm[threadIdx.x] = (i < n) ? cnt[i] : 0;
    __syncthreads();
    for (int s = 128; s > 0; s >>= 1) {
        if (threadIdx.x < s) sm[threadIdx.x] += sm[threadIdx.x + s];
        __syncthreads();
    }
    if (threadIdx.x == 0) bsum[blockIdx.x] = sm[0];
}

__global__ void k_bscan(const int* __restrict__ bsum, int* __restrict__ boff, int nb) {
    __shared__ int sm[256];
    int tid = threadIdx.x;
    int v = (tid < nb) ? bsum[tid] : 0;
    sm[tid] = v;
    __syncthreads();
    for (int s = 1; s < 256; s <<= 1) {
        int t = (tid >= s) ? sm[tid - s] : 0;
        __syncthreads();
        sm[tid] += t;
        __syncthreads();
    }
    if (tid < nb) boff[tid] = sm[tid] - v;
}

__global__ void k_scanblk(const int* __restrict__ cnt, const int* __restrict__ boff,
                          int* __restrict__ rp, int n) {
    __shared__ int sm[256];
    int tid = threadIdx.x;
    int i = blockIdx.x * 256 + tid;
    int v = (i < n) ? cnt[i] : 0;
    sm[tid] = v;
    __syncthreads();
    for (int s = 1; s < 256; s <<= 1) {
        int t = (tid >= s) ? sm[tid - s] : 0;
        __syncthreads();
        sm[tid] += t;
        __syncthreads();
    }
    int incl = sm[tid];
    int base = boff[blockIdx.x];
    if (i < n) rp[i] = base + incl - v;
    if (i == n - 1) rp[n] = base + incl;
}

__global__ void k_fill(const int* __restrict__ row, const int* __restrict__ col,
                       const int* __restrict__ rp, int* __restrict__ cur,
                       int* __restrict__ src, int E) {
    int e = blockIdx.x * blockDim.x + threadIdx.x;
    if (e >= E) return;
    int c = col[e];
    int pos = rp[c] + atomicAdd(&cur[c], 1);
    src[pos] = row[e];
}

__global__ void k_dinv(const int* __restrict__ rp, float* __restrict__ dinv, int n) {
    int v = blockIdx.x * blockDim.x + threadIdx.x;
    if (v < n) dinv[v] = rsqrtf((float)(rp[v + 1] - rp[v] + 1));  // +1 self-loop
}

// ---------------- weight transpose + bf16 cast: W[K][N] f32 -> Wt[N][K] bf16 ----------------
__global__ void k_wt(const float* __restrict__ W, u16* __restrict__ Wt, int K, int N) {
    __shared__ u16 sm[32][33];
    const float* Wl = W + (size_t)blockIdx.z * K * N;
    u16* Wtl = Wt + (size_t)blockIdx.z * K * N;
    int k0 = blockIdx.y * 32, n0 = blockIdx.x * 32;
    int tx = threadIdx.x, ty = threadIdx.y;  // 32 x 8
#pragma unroll
    for (int r = 0; r < 32; r += 8)
        sm[ty + r][tx] = f2bf(Wl[(size_t)(k0 + ty + r) * N + n0 + tx]);
    __syncthreads();
#pragma unroll
    for (int r = 0; r < 32; r += 8)
        Wtl[(size_t)(n0 + ty + r) * K + k0 + tx] = sm[tx][ty + r];
}

// outW [H=256][C=112] f32 -> outWt [128][256] bf16 (rows >= C zero); pad bias to 128
__global__ void k_outwt(const float* __restrict__ outW, const float* __restrict__ outb,
                        u16* __restrict__ outWt, float* __restrict__ obb) {
    int idx = blockIdx.x * 256 + threadIdx.x;     // 128*256
    if (idx >= 128 * 256) return;
    int n = idx >> 8, k = idx & 255;
    float v = (n < CC) ? outW[(size_t)k * CC + n] : 0.f;
    outWt[(size_t)n * HH + k] = f2bf(v);
    if (idx < 128) obb[idx] = (idx < CC) ? outb[idx] : 0.f;
}

// ---------------- fp32 -> bf16 cast ----------------
__global__ void k_xcast(const float* __restrict__ x, u16* __restrict__ xb, int n4) {
    int i = blockIdx.x * blockDim.x + threadIdx.x;
    if (i >= n4) return;
    float4 v = ((const float4*)x)[i];
    ushort4 o;
    o.x = f2bf(v.x); o.y = f2bf(v.y); o.z = f2bf(v.z); o.w = f2bf(v.w);
    *(ushort4*)(xb + ((size_t)i << 2)) = o;
}

// ---------------- bf16 MFMA GEMM: C = A @ Bt^T + bias, optional per-row scale ----------------
template <bool F32OUT>
__global__ __launch_bounds__(256) void k_gemm_bf16(const u16* __restrict__ A,
                                                   const u16* __restrict__ Bt,
                                                   const float* __restrict__ bias,
                                                   const float* __restrict__ rowscale,
                                                   void* __restrict__ Cout,
                                                   int M, int Nc, int K) {
    __shared__ u16 As[128 * 32];
    __shared__ u16 Bs[128 * 32];
    const int tid = threadIdx.x;
    const int w = tid >> 6, lane = tid & 63;
    const int m0 = blockIdx.x * 128;
    const int n0 = blockIdx.y * 128;
    const int wr = (w >> 1) * 64, wc = (w & 1) * 64;
    const int lm = lane & 15, lq = lane >> 4;

    f32x4 acc[4][4];
#pragma unroll
    for (int i = 0; i < 4; ++i)
#pragma unroll
        for (int j = 0; j < 4; ++j) acc[i][j] = (f32x4){0.f, 0.f, 0.f, 0.f};

    const int srow = w * 16 + (lane >> 2);
    const int scol = (lane & 3) * 8;

    for (int k0 = 0; k0 < K; k0 += 32) {
        int gm = m0 + srow;        if (gm >= M) gm = M - 1;
        gload16(A + (size_t)gm * K + k0 + scol, As + (size_t)(w * 64) * 8);
        int gm2 = m0 + 64 + srow;  if (gm2 >= M) gm2 = M - 1;
        gload16(A + (size_t)gm2 * K + k0 + scol, As + (size_t)(256 + w * 64) * 8);
        gload16(Bt + (size_t)(n0 + srow) * K + k0 + scol, Bs + (size_t)(w * 64) * 8);
        gload16(Bt + (size_t)(n0 + 64 + srow) * K + k0 + scol, Bs + (size_t)(256 + w * 64) * 8);
        __syncthreads();

        bf16x8 af[4], bfr[4];
#pragma unroll
        for (int i = 0; i < 4; ++i)
            af[i] = *(const bf16x8*)(As + (wr + i * 16 + lm) * 32 + lq * 8);
#pragma unroll
        for (int j = 0; j < 4; ++j)
            bfr[j] = *(const bf16x8*)(Bs + (wc + j * 16 + lm) * 32 + lq * 8);
#pragma unroll
        for (int i = 0; i < 4; ++i)
#pragma unroll
            for (int j = 0; j < 4; ++j)
                acc[i][j] = __builtin_amdgcn_mfma_f32_16x16x32_bf16(af[i], bfr[j], acc[i][j], 0, 0, 0);
        __syncthreads();
    }

    // epilogue: C/D layout col=lane&15, row=(lane>>4)*4+reg  [m89-verified]
#pragma unroll
    for (int j = 0; j < 4; ++j) {
        int gc = n0 + wc + j * 16 + lm;
        float bj = (gc < Nc) ? bias[gc] : 0.f;
#pragma unroll
        for (int i = 0; i < 4; ++i) {
#pragma unroll
            for (int r = 0; r < 4; ++r) {
                int gr = m0 + wr + i * 16 + lq * 4 + r;
                if (gr < M && gc < Nc) {
                    float rs = rowscale ? rowscale[gr] : 1.0f;
                    float val = (acc[i][j][r] + bj) * rs;
                    if (F32OUT)
                        ((float*)Cout)[(size_t)gr * Nc + gc] = val;
                    else
                        ((u16*)Cout)[(size_t)gr * Nc + gc] = f2bf(val);
                }
            }
        }
    }
}

// ---------------- gather SpMM, premultiplied t' = dinv[r]*t[r] (bf16); bf16 out --------------
__global__ __launch_bounds__(256) void k_spmm_bf16(const u16* __restrict__ t,
                                                   const int* __restrict__ rp,
                                                   const int* __restrict__ src,
                                                   const float* __restrict__ dinv,
                                                   u16* __restrict__ hpre) {
    int gt = blockIdx.x * blockDim.x + threadIdx.x;
    int v = gt >> 6;            // one wave per node
    int lane = threadIdx.x & 63;
    if (v >= NN) return;
    int c = lane << 2;          // 4 cols per lane
    const u16* tp = t + c;
    float dv = dinv[v];
    uint2 a = *(const uint2*)(tp + (size_t)v * HH);
    float4 accv;
    accv.x = bflo(a.x); accv.y = bfhi(a.x);
    accv.z = bflo(a.y); accv.w = bfhi(a.y);
    int beg = rp[v], end = rp[v + 1];
    int j = beg;
    for (; j + 8 <= end; j += 8) {
        int s0 = src[j + 0], s1 = src[j + 1], s2 = src[j + 2], s3 = src[j + 3];
        int s4 = src[j + 4], s5 = src[j + 5], s6 = src[j + 6], s7 = src[j + 7];
        uint2 b0 = *(const uint2*)(tp + (size_t)s0 * HH);
        uint2 b1 = *(const uint2*)(tp + (size_t)s1 * HH);
        uint2 b2 = *(const uint2*)(tp + (size_t)s2 * HH);
        uint2 b3 = *(const uint2*)(tp + (size_t)s3 * HH);
        uint2 b4 = *(const uint2*)(tp + (size_t)s4 * HH);
        uint2 b5 = *(const uint2*)(tp + (size_t)s5 * HH);
        uint2 b6 = *(const uint2*)(tp + (size_t)s6 * HH);
        uint2 b7 = *(const uint2*)(tp + (size_t)s7 * HH);
        accv.x += bflo(b0.x) + bflo(b1.x) + bflo(b2.x) + bflo(b3.x)
                + bflo(b4.x) + bflo(b5.x) + bflo(b6.x) + bflo(b7.x);
        accv.y += bfhi(b0.x) + bfhi(b1.x) + bfhi(b2.x) + bfhi(b3.x)
                + bfhi(b4.x) + bfhi(b5.x) + bfhi(b6.x) + bfhi(b7.x);
        accv.z += bflo(b0.y) + bflo(b1.y) + bflo(b2.y) + bflo(b3.y)
                + bflo(b4.y) + bflo(b5.y) + bflo(b6.y) + bflo(b7.y);
        accv.w += bfhi(b0.y) + bfhi(b1.y) + bfhi(b2.y) + bfhi(b3.y)
                + bfhi(b4.y) + bfhi(b5.y) + bfhi(b6.y) + bfhi(b7.y);
    }
    for (; j + 2 <= end; j += 2) {
        int s0 = src[j], s1 = src[j + 1];
        uint2 b0 = *(const uint2*)(tp + (size_t)s0 * HH);
        uint2 b1 = *(const uint2*)(tp + (size_t)s1 * HH);
        accv.x += bflo(b0.x) + bflo(b1.x);
        accv.y += bfhi(b0.x) + bfhi(b1.x);
        accv.z += bflo(b0.y) + bflo(b1.y);
        accv.w += bfhi(b0.y) + bfhi(b1.y);
    }
    if (j < end) {
        int s0 = src[j];
        uint2 b0 = *(const uint2*)(tp + (size_t)s0 * HH);
        accv.x += bflo(b0.x); accv.y += bfhi(b0.x);
        accv.z += bflo(b0.y); accv.w += bfhi(b0.y);
    }
    ushort4 o;
    o.x = f2bf(accv.x * dv); o.y = f2bf(accv.y * dv);
    o.z = f2bf(accv.z * dv); o.w = f2bf(accv.w * dv);
    *(ushort4*)(hpre + (size_t)v * HH + c) = o;
}

// ---------------- BatchNorm stats over bf16 hpre ----------------
#define RPB 128
__global__ void k_bnstats(const u16* __restrict__ h, float* __restrict__ s,
                          float* __restrict__ q) {
    int col = threadIdx.x;       // 256 threads == H columns
    int r0 = blockIdx.x * RPB;
    int r1 = r0 + RPB; if (r1 > NN) r1 = NN;
    float sum = 0.f, sq = 0.f;
    for (int r = r0; r < r1; ++r) {
        float v = bf1(h[(size_t)r * HH + col]);
        sum += v;
        sq = fmaf(v, v, sq);
    }
    atomicAdd(&s[col], sum);
    atomicAdd(&q[col], sq);
}

// ---------------- normalize + ReLU + weighted residual (fp32 acc); writes bf16 h ------------
__global__ void k_bnnorm(const u16* __restrict__ hpre, float* __restrict__ acc,
                         u16* __restrict__ hb,
                         const float* __restrict__ s, const float* __restrict__ q,
                         const float* __restrict__ gamma, const float* __restrict__ beta,
                         const float* __restrict__ wArr, int layer) {
    int idx = blockIdx.x * blockDim.x + threadIdx.x;
    if (idx >= NN * (HH / 4)) return;
    int c = (idx & 63) << 2;
    const float invN = 1.0f / (float)NN;
    float w = wArr[layer];
    ushort4 hv = ((const ushort4*)hpre)[idx];
    float4 av = ((const float4*)acc)[idx];
    u16* hp = &hv.x;
    float* ap = &av.x;
    ushort4 o;
    u16* op = &o.x;
#pragma unroll
    for (int k = 0; k < 4; ++k) {
        float mu = s[c + k] * invN;
        float var = q[c + k] * invN - mu * mu;
        float g = gamma[c + k];
        float b = beta[c + k];
        float v = (bf1(hp[k]) - mu) * rsqrtf(var + EPSB) * g + b;
        v = fmaxf(v, 0.f);
        ap[k] = fmaf(w, v, ap[k]);
        op[k] = f2bf(v);
    }
    ((float4*)acc)[idx] = av;
    *(ushort4*)(hb + ((size_t)idx << 2)) = o;
}

// ---------------- fp32 acc -> bf16 cast ----------------
__global__ void k_acast(const float* __restrict__ acc, u16* __restrict__ accb, int n4) {
    int i = blockIdx.x * blockDim.x + threadIdx.x;
    if (i >= n4) return;
    float4 v = ((const float4*)acc)[i];
    ushort4 o;
    o.x = f2bf(v.x); o.y = f2bf(v.y); o.z = f2bf(v.z); o.w = f2bf(v.w);
    *(ushort4*)(accb + ((size_t)i << 2)) = o;
}

// ---------------- softmax of the 8 layer weights ----------------
__global__ void k_softmaxw(const float* __restrict__ lw, float* __restrict__ wArr) {
    if (threadIdx.x == 0 && blockIdx.x == 0) {
        float m = -3.0e38f;
        for (int i = 0; i < LL; ++i) m = fmaxf(m, lw[i]);
        float e[LL]; float sum = 0.f;
        for (int i = 0; i < LL; ++i) { e[i] = expf(lw[i] - m); sum += e[i]; }
        for (int i = 0; i < LL; ++i) wArr[i] = e[i] / sum;
    }
}

// ---------------- log_softmax rows ----------------
__global__ __launch_bounds__(256) void k_logsoftmax(const float* __restrict__ z,
                                                    float* __restrict__ out) {
    int gt = blockIdx.x * blockDim.x + threadIdx.x;
    int v = gt >> 6;
    int lane = threadIdx.x & 63;
    if (v >= NN) return;
    const float* row = z + (size_t)v * CC;
    float v0 = row[lane];
    float v1 = (lane + 64 < CC) ? row[lane + 64] : -3.0e38f;
    float m = fmaxf(v0, v1);
#pragma unroll
    for (int d = 1; d < 64; d <<= 1) m = fmaxf(m, __shfl_xor(m, d, 64));
    float e = expf(v0 - m) + ((lane + 64 < CC) ? expf(v1 - m) : 0.f);
#pragma unroll
    for (int d = 1; d < 64; d <<= 1) e += __shfl_xor(e, d, 64);
    float lse = m + logf(e);
    out[(size_t)v * CC + lane] = v0 - lse;
    if (lane + 64 < CC) out[(size_t)v * CC + lane + 64] = v1 - lse;
}

extern "C" void kernel_launch(void* const* d_in, const int* in_sizes, int n_in,
                              void* d_out, int out_size, void* d_ws, size_t ws_size,
                              hipStream_t stream) {
    const float* x     = (const float*)d_in[0];
    const int*   e1    = (const int*)d_in[1];
    const int*   e2    = (const int*)d_in[2];
    const float* inW   = (const float*)d_in[3];
    const float* inb   = (const float*)d_in[4];
    const float* convW = (const float*)d_in[5];
    const float* convB = (const float*)d_in[6];
    const float* gamma = (const float*)d_in[7];
    const float* beta  = (const float*)d_in[8];
    const float* outW  = (const float*)d_in[9];
    const float* outb  = (const float*)d_in[10];
    const float* lw    = (const float*)d_in[11];

    char* ws = (char*)d_ws;
    size_t off = 0;
    auto alloc = [&](size_t bytes) -> void* {
        void* p = ws + off;
        off = (off + bytes + 255) & ~(size_t)255;
        return p;
    };
    // total ~137 MB (Round-3's 162 MB layout passed; Round-4's 332 MB crashed)
    u16*   hb    = (u16*)alloc((size_t)NN * HH * 2);     // bf16 h (GEMM A)
    u16*   tb    = (u16*)alloc((size_t)NN * HH * 2);     // bf16 t'; alias xb/accb
    u16*   hpre  = (u16*)alloc((size_t)NN * HH * 2);     // spmm out; alias logits(f32)
    float* acc   = (float*)alloc((size_t)NN * HH * 4);   // fp32 residual accumulator
    u16*   convWt= (u16*)alloc((size_t)LL * HH * HH * 2);
    u16*   inWt  = (u16*)alloc((size_t)HH * FIN * 2);
    u16*   outWt = (u16*)alloc((size_t)128 * HH * 2);
    float* obb   = (float*)alloc(128 * 4);
    float* dinv1 = (float*)alloc((size_t)NN * 4);
    float* dinv2 = (float*)alloc((size_t)NN * 4);
    int*   rp1   = (int*)alloc((size_t)(NN + 1) * 4);
    int*   rp2   = (int*)alloc((size_t)(NN + 1) * 4);
    int*   src1  = (int*)alloc((size_t)EE * 4);
    int*   src2  = (int*)alloc((size_t)EE * 4);
    int*   cntz  = (int*)alloc((size_t)4 * NN * 4);      // cnt1a,cnt1b,cnt2a,cnt2b
    int*   bsum  = (int*)alloc(256 * 4);
    int*   boff  = (int*)alloc(256 * 4);
    float* bnsq  = (float*)alloc((size_t)2 * LL * HH * 4);
    float* wArr  = (float*)alloc(64);
    u16*   xb    = tb;            // x_bf16 dead once layer-0 conv GEMM writes tb
    u16*   accb  = tb;            // bf16(acc) after last spmm: tb free
    float* logits = (float*)hpre; // fp32 logits: hpre free after last bnnorm

    int* cnt1a = cntz;
    int* cnt1b = cntz + NN;
    int* cnt2a = cntz + 2 * NN;
    int* cnt2b = cntz + 3 * NN;

    const int EB = (EE + 255) / 256;
    const int NB = (NN + 255) / 256;

    hipMemsetAsync(cntz, 0, (size_t)4 * NN * 4, stream);
    hipMemsetAsync(bnsq, 0, (size_t)2 * LL * HH * 4, stream);
    hipMemsetAsync(acc, 0, (size_t)NN * HH * 4, stream);

    // CSR adjacency 1
    k_count<<<EB, 256, 0, stream>>>(e1 + EE, cnt1a, EE);
    k_bsum<<<NBLK, 256, 0, stream>>>(cnt1a, bsum, NN);
    k_bscan<<<1, 256, 0, stream>>>(bsum, boff, NBLK);
    k_scanblk<<<NBLK, 256, 0, stream>>>(cnt1a, boff, rp1, NN);
    k_fill<<<EB, 256, 0, stream>>>(e1, e1 + EE, rp1, cnt1b, src1, EE);
    k_dinv<<<NB, 256, 0, stream>>>(rp1, dinv1, NN);

    // CSR adjacency 2
    k_count<<<EB, 256, 0, stream>>>(e2 + EE, cnt2a, EE);
    k_bsum<<<NBLK, 256, 0, stream>>>(cnt2a, bsum, NN);
    k_bscan<<<1, 256, 0, stream>>>(bsum, boff, NBLK);
    k_scanblk<<<NBLK, 256, 0, stream>>>(cnt2a, boff, rp2, NN);
    k_fill<<<EB, 256, 0, stream>>>(e2, e2 + EE, rp2, cnt2b, src2, EE);
    k_dinv<<<NB, 256, 0, stream>>>(rp2, dinv2, NN);

    k_softmaxw<<<1, 64, 0, stream>>>(lw, wArr);

    // weight prep
    {
        dim3 g(HH / 32, HH / 32, LL);
        dim3 b(32, 8);
        k_wt<<<g, b, 0, stream>>>(convW, convWt, HH, HH);
        dim3 g2(HH / 32, FIN / 32, 1);
        k_wt<<<g2, b, 0, stream>>>(inW, inWt, FIN, HH);
        k_outwt<<<128, 256, 0, stream>>>(outW, outb, outWt, obb);
    }
    k_xcast<<<(NN * FIN / 4 + 255) / 256, 256, 0, stream>>>(x, xb, NN * FIN / 4);

    const int MT = (NN + 127) / 128;  // 391
    // input FC: hb = bf16( x @ inW + inb )
    {
        dim3 g(MT, HH / 128);
        k_gemm_bf16<false><<<g, 256, 0, stream>>>(xb, inWt, inb, nullptr, hb, NN, HH, FIN);
    }

    const int SPB = (NN * 64 + 255) / 256;
    const int ELB = (NN * (HH / 4) + 255) / 256;
    for (int i = 0; i < LL; ++i) {
        const int* rp = (i < LL / 2) ? rp1 : rp2;
        const int* sr = (i < LL / 2) ? src1 : src2;
        const float* dv = (i < LL / 2) ? dinv1 : dinv2;
        float* bns = bnsq + (size_t)i * 2 * HH;
        float* bnq = bns + HH;
        dim3 g(MT, HH / 128);
        // tb = bf16( dinv[r] * (hb @ convW_i + convB_i) )
        k_gemm_bf16<false><<<g, 256, 0, stream>>>(hb, convWt + (size_t)i * HH * HH,
                                                  convB + (size_t)i * HH, dv, tb, NN, HH, HH);
        k_spmm_bf16<<<SPB, 256, 0, stream>>>(tb, rp, sr, dv, hpre);
        k_bnstats<<<(NN + RPB - 1) / RPB, 256, 0, stream>>>(hpre, bns, bnq);
        k_bnnorm<<<ELB, 256, 0, stream>>>(hpre, acc, hb, bns, bnq,
                                          gamma + (size_t)i * HH, beta + (size_t)i * HH,
                                          wArr, i);
    }

    // accb = bf16(acc)  (tb is free after the last spmm)
    k_acast<<<ELB, 256, 0, stream>>>(acc, accb, NN * (HH / 4));

    // out FC: logits = accb @ outWt^T + obb   (fp32 store into hpre, Nc=112)
    {
        dim3 g(MT, 1);
        k_gemm_bf16<true><<<g, 256, 0, stream>>>(accb, outWt, obb, nullptr, logits, NN, CC, HH);
    }
    k_logsoftmax<<<SPB, 256, 0, stream>>>(logits, (float*)d_out);
}